// Round 13
// baseline (40.122 us; speedup 1.0000x reference)
//
#include <hip/hip_runtime.h>

// RetinaNet target encoder for MI355X — round 13: round-12 structure with
//   (1) GT_PER_BLK 64 -> 128 (half the prolog/prior-reload redundancy, half
//       the per-prior u64 atomics), 2-wave order-preserving compaction
//   (2) phase-2 predication on live rows (no dead -1 fills, dead waves skip)
//
// Inputs: bboxes [N,4] f32 xyxy, labels [N] i32, priors [M,4] f32 cxcywh.
// Outputs (concat): reg_targets [M,4] f32, cls_targets [M] (written as f32).
//
// N = 1024, M = 49104. Grid (8 chunks, 192 prior-blocks, heavy-first).
// Block = 256 priors x 128 GTs:
//   - block bbox over the 256 prior boxes (wave butterfly + LDS + barrier)
//   - waves 0-1 test the 128 GTs vs block bbox; failing GT => ALL pair-IoUs
//     in this block are exactly 0.0f in the reference (disjoint => clamped
//     w/h == 0) => skipping is bit-exact. ballot+prefix (+wave-1 offset by
//     wave-0 count) -> compacted ASCENDING list of GT boxes+areas+indices.
//   - per 16-row batch: phase 1: IoU -> per-prior argmax regs + LDS tile;
//     phase 2 (waves with live rows only): 16 lanes per row scan the tile
//     transposed, 4-step shfl merge, exact (max iou, min m) tie-break ->
//     atomicMax partG[gt].
// Tie semantics == numpy everywhere: strict > over ascending index; packed
// u64 (iou_bits<<32)|(0xFFFFFFFF-idx) max == (max iou, smallest idx);
// forced-assign duplicates: atomicMax(n) == numpy last-write-wins.
// part1 init = packiou(0,0): an all-zero prior row decodes to (iou 0, n 0)
// = numpy argmax over zeros; best==0 chunks skip their atomic (can't beat it).

static constexpr float NEG_THRESH = 0.4f;
static constexpr float POS_THRESH = 0.5f;
static constexpr int N_GT = 1024;
static constexpr int GT_PER_BLK = 128;
static constexpr int NCHUNK = N_GT / GT_PER_BLK;   // 8
static constexpr int MPAD = 49152;                 // M rounded up to 256
static constexpr int BLK = 256;                    // priors per block
static constexpr int NB = MPAD / BLK;              // 192 prior blocks
static constexpr int T_ROWS = 16;                  // tile rows per batch
static constexpr int STRIDE = 264;                 // 2-way banks max (free)

__device__ __forceinline__ unsigned long long packiou(float iou, unsigned idx_) {
    return ((unsigned long long)__float_as_uint(iou) << 32) |
           (unsigned long long)(0xFFFFFFFFu - idx_);
}

// ---------------- Init: tiny, replaces hipMemsetAsync ------------------------
__global__ void __launch_bounds__(256) init_kernel(
        unsigned long long* __restrict__ part1,
        unsigned long long* __restrict__ partG,
        int* __restrict__ force_n) {
    int i = blockIdx.x * 256 + threadIdx.x;
    part1[i] = 0x00000000FFFFFFFFull;   // packiou(0.0f, 0)
    force_n[i] = -1;
    if (i < N_GT) partG[i] = 0ull;
}

// ---------------- Fused kernel ----------------
__global__ void __launch_bounds__(256) fused_kernel(
        const float* __restrict__ bboxes,
        const float* __restrict__ priors,
        unsigned long long* __restrict__ part1,   // [MPAD] init packiou(0,0)
        unsigned long long* __restrict__ partG,   // [N_GT] init 0, atomicMax
        int M) {
#pragma clang fp contract(off)
    __shared__ float tile[T_ROWS][STRIDE];        // 16.9 KB
    __shared__ float sgx1[GT_PER_BLK], sgy1[GT_PER_BLK];
    __shared__ float sgx2[GT_PER_BLK], sgy2[GT_PER_BLK], sgar[GT_PER_BLK];
    __shared__ unsigned short sidx[GT_PER_BLK];
    __shared__ float sbb[4][4];
    __shared__ int scnt[2];

    int tid = threadIdx.x;
    int lane = tid & 63;
    int wid = tid >> 6;
    int bx = (NB - 1) - blockIdx.y;               // heavy levels dispatch first
    int n0 = blockIdx.x * GT_PER_BLK;
    int m = bx * BLK + tid;
    bool valid = (m < M);

    float4 p = valid ? reinterpret_cast<const float4*>(priors)[m]
                     : make_float4(0.f, 0.f, 0.f, 0.f);
    float bx1 = p.x - p.z / 2.0f;
    float by1 = p.y - p.w / 2.0f;
    float bx2 = p.x + p.z / 2.0f;
    float by2 = p.y + p.w / 2.0f;
    float area_b = (bx2 - bx1) * (by2 - by1);

    // ---- block bbox over 256 prior boxes ----
    float mnx = valid ? bx1 : 1e30f;
    float mny = valid ? by1 : 1e30f;
    float mxx = valid ? bx2 : -1e30f;
    float mxy = valid ? by2 : -1e30f;
#pragma unroll
    for (int mk = 1; mk < 64; mk <<= 1) {
        mnx = fminf(mnx, __shfl_xor(mnx, mk));
        mny = fminf(mny, __shfl_xor(mny, mk));
        mxx = fmaxf(mxx, __shfl_xor(mxx, mk));
        mxy = fmaxf(mxy, __shfl_xor(mxy, mk));
    }
    if (lane == 0) {
        sbb[wid][0] = mnx; sbb[wid][1] = mny; sbb[wid][2] = mxx; sbb[wid][3] = mxy;
    }
    __syncthreads();

    // ---- waves 0-1: test 128 GTs, 2-segment ascending compaction ----
    bool hit = false;
    unsigned long long bal = 0;
    if (tid < GT_PER_BLK) {
        float BX1 = fminf(fminf(sbb[0][0], sbb[1][0]), fminf(sbb[2][0], sbb[3][0]));
        float BY1 = fminf(fminf(sbb[0][1], sbb[1][1]), fminf(sbb[2][1], sbb[3][1]));
        float BX2 = fmaxf(fmaxf(sbb[0][2], sbb[1][2]), fmaxf(sbb[2][2], sbb[3][2]));
        float BY2 = fmaxf(fmaxf(sbb[0][3], sbb[1][3]), fmaxf(sbb[2][3], sbb[3][3]));
        float4 g = reinterpret_cast<const float4*>(bboxes)[n0 + tid];
        hit = (g.x < BX2) & (g.z > BX1) & (g.y < BY2) & (g.w > BY1);
        bal = __ballot(hit);
        if (lane == 0) scnt[wid] = __popcll(bal);
        if (hit) {
            // position within this wave's segment; wave-1 offset added after
            // the barrier (scnt[0] not yet visible here).
            int pos = __popcll(bal & ((1ull << lane) - 1ull));
            // stash pos in a register; write after barrier
            // (we re-derive pos below instead of stashing — bal is in regs)
        }
        // keep g in registers for the post-barrier write
        // (compiler keeps float4 g live; cheap)
        if (false) {}
        // store g components via registers below
        // NOTE: we re-load nothing; write happens after barrier using g/bal.
        // Fall through with g in scope:
        __syncthreads();
        if (hit) {
            int pos = (wid ? scnt[0] : 0) +
                      __popcll(bal & ((1ull << lane) - 1ull));
            sgx1[pos] = g.x; sgy1[pos] = g.y;
            sgx2[pos] = g.z; sgy2[pos] = g.w;
            sgar[pos] = (g.z - g.x) * (g.w - g.y);
            sidx[pos] = (unsigned short)tid;
        }
    } else {
        __syncthreads();   // matching barrier for waves 2-3
    }
    __syncthreads();       // compacted list visible to all
    int cnt = scnt[0] + scnt[1];

    float best = 0.0f;    // iou >= 0 everywhere
    int bestn = n0;

    int row = tid >> 4;   // phase-2: 16 lanes per row
    int sub = tid & 15;
    int m0 = bx * BLK;

    int nfull = cnt >> 4;
    int tail = cnt & 15;

    for (int b = 0; b <= nfull; ++b) {
        int rows = (b < nfull) ? T_ROWS : tail;
        if (rows == 0) break;
        int base = b * T_ROWS;

        // ---- phase 1: straight-line IoU rows, LDS-broadcast GT data ----
#pragma unroll
        for (int r = 0; r < T_ROWS; ++r) {
            if (r < rows) {
                int idx = base + r;
                float gx1 = sgx1[idx], gy1 = sgy1[idx];
                float gx2 = sgx2[idx], gy2 = sgy2[idx];
                float ga  = sgar[idx];
                int   jn  = n0 + (int)sidx[idx];

                float ltx = fmaxf(gx1, bx1);
                float lty = fmaxf(gy1, by1);
                float rbx = fminf(gx2, bx2);
                float rby = fminf(gy2, by2);
                float w = rbx - ltx; if (w < 0.0f) w = 0.0f;
                float h = rby - lty; if (h < 0.0f) h = 0.0f;
                float inter = w * h;
                float iou = inter / (ga + area_b - inter);

                // strict > over ascending idx (list ascending) == first-max
                if (iou > best) { best = iou; bestn = jn; }
                tile[r][tid] = valid ? iou : -1.0f;
            }
            // dead rows: nothing written; phase 2 never reads them
        }
        __syncthreads();

        // ---- phase 2: only waves owning live rows participate ----
        if ((wid << 2) < rows) {
            if (row < rows) {
                float bi = -2.0f;
                int bm = 0;
#pragma unroll
                for (int k = 0; k < BLK / 16; ++k) {
                    int col = sub + 16 * k;             // ascending col
                    float v = tile[row][col];
                    if (v > bi) { bi = v; bm = col; }   // strict >: min col
                }
#pragma unroll
                for (int msk = 1; msk < 16; msk <<= 1) {
                    float oi = __shfl_xor(bi, msk);
                    int om = __shfl_xor(bm, msk);
                    if (oi > bi || (oi == bi && om < bm)) { bi = oi; bm = om; }
                }
                if (sub == 0 && bi > 0.0f) {
                    int jr = (int)sidx[base + row];
                    atomicMax(&partG[n0 + jr], packiou(bi, (unsigned)(m0 + bm)));
                }
            }
        }
        __syncthreads();   // tile reused next batch
    }

    // best == 0 chunks skip: init packiou(0,0) >= packiou(0,n) for all n >= 0.
    if (valid && best > 0.0f) {
        atomicMax(&part1[m], packiou(best, (unsigned)bestn));
    }
}

// ---------------- RS: per-GT winner -> forced-assignment scatter -------------
__global__ void rs_kernel(const unsigned long long* __restrict__ partG,
                          int* __restrict__ force_n) {
    int n = blockIdx.x * blockDim.x + threadIdx.x;
    if (n >= N_GT) return;
    unsigned long long v = partG[n];
    int m = (int)(0xFFFFFFFFu - (unsigned)(v & 0xFFFFFFFFull));
    atomicMax(&force_n[m], n);   // duplicate priors: last write in np == max n
}

// ---------------- E: decode per-prior winner + encode ------------------------
__global__ void __launch_bounds__(256) encode_kernel(
        const float* __restrict__ bboxes,
        const int* __restrict__ labels,
        const float* __restrict__ priors,
        const unsigned long long* __restrict__ part1,
        const int* __restrict__ force_n,
        float* __restrict__ out, int M) {
#pragma clang fp contract(off)
    int m = blockIdx.x * 256 + threadIdx.x;
    if (m >= M) return;

    unsigned long long v = part1[m];
    float iou = __uint_as_float((unsigned)(v >> 32));
    int mid = (int)(0xFFFFFFFFu - (unsigned)(v & 0xFFFFFFFFull));

    int f = force_n[m];
    if (f >= 0) { mid = f; iou = POS_THRESH; }

    float4 g = reinterpret_cast<const float4*>(bboxes)[mid];
    float mcx = (g.x + g.z) / 2.0f;
    float mcy = (g.y + g.w) / 2.0f;
    float mw = g.z - g.x;
    float mh = g.w - g.y;

    float4 p = reinterpret_cast<const float4*>(priors)[m];
    float dcx = ((mcx - p.x) / p.z) / 0.1f;
    float dcy = ((mcy - p.y) / p.w) / 0.1f;
    float dw = logf(mw / p.z) / 0.2f;
    float dh = logf(mh / p.w) / 0.2f;

    reinterpret_cast<float4*>(out)[m] = make_float4(dcx, dcy, dw, dh);

    int cls = labels[mid];
    if (iou < POS_THRESH) cls = -1;
    if (iou < NEG_THRESH) cls = 0;
    out[(size_t)4 * M + m] = (float)cls;
}

extern "C" void kernel_launch(void* const* d_in, const int* in_sizes, int n_in,
                              void* d_out, int out_size, void* d_ws, size_t ws_size,
                              hipStream_t stream) {
    const float* bboxes = (const float*)d_in[0];
    const int* labels = (const int*)d_in[1];
    const float* priors = (const float*)d_in[2];
    int M = in_sizes[2] / 4;
    float* out = (float*)d_out;

    // Workspace (~0.6 MB): part1 [MPAD u64] | partG [N_GT u64] | force_n [MPAD int]
    char* ws = (char*)d_ws;
    unsigned long long* part1 = (unsigned long long*)ws;
    unsigned long long* partG = (unsigned long long*)(ws + (size_t)MPAD * 8);
    int* force_n = (int*)(ws + (size_t)MPAD * 8 + (size_t)N_GT * 8);

    init_kernel<<<MPAD / 256, 256, 0, stream>>>(part1, partG, force_n);
    fused_kernel<<<dim3(NCHUNK, NB), 256, 0, stream>>>(bboxes, priors, part1,
                                                       partG, M);
    rs_kernel<<<(N_GT + 255) / 256, 256, 0, stream>>>(partG, force_n);
    encode_kernel<<<(MPAD + 255) / 256, 256, 0, stream>>>(bboxes, labels, priors,
                                                          part1, force_n, out, M);
}